// Round 6
// baseline (219.312 us; speedup 1.0000x reference)
//
#include <hip/hip_runtime.h>
#include <hip/hip_bf16.h>

#define BB 4
#define CC 64
#define HH 128
#define WW 128
#define HW (HH * WW)
#define OCP 20  // offset channels, padded (18 used)

typedef short bf16x8 __attribute__((ext_vector_type(8)));
typedef float f32x4 __attribute__((ext_vector_type(4)));
typedef float f32x2 __attribute__((ext_vector_type(2)));

static __device__ __forceinline__ short f2bf(float f) {
  __hip_bfloat16 h = __float2bfloat16(f);
  return __builtin_bit_cast(short, h);
}
static __device__ __forceinline__ float bf2f(short s) {
  unsigned int u = ((unsigned int)(unsigned short)s) << 16;
  return __builtin_bit_cast(float, u);
}

// NCHW f32 -> NHWC bf16 for two tensors. Block = 64 px x 64 c tile.
__global__ __launch_bounds__(256) void cast_nhwc_kernel(
    const float* __restrict__ a, const float* __restrict__ b,
    short* __restrict__ oa, short* __restrict__ ob) {
  __shared__ float tile[64][68];
  const int bid = blockIdx.x;        // 1024 blocks
  const int bb = bid >> 8;           // batch
  const int hw0 = (bid & 255) * 64;  // 64-px stripe
  const int t = threadIdx.x;
  for (int s = 0; s < 2; s++) {
    const float* src = s ? b : a;
    short* dst = s ? ob : oa;
    if (s) __syncthreads();
    {
      const int lp = t & 15;  // 16 lanes x float4 = 64 px
      for (int c = (t >> 4); c < 64; c += 16) {
        float4 v = *(const float4*)&src[((size_t)(bb * 64 + c)) * HW + hw0 + lp * 4];
        *(float4*)&tile[c][lp * 4] = v;
      }
    }
    __syncthreads();
    {
      const int px = t >> 2;
      const int seg = t & 3;
      bf16x8 s0, s1;
#pragma unroll
      for (int i = 0; i < 8; i++) s0[i] = f2bf(tile[seg * 16 + i][px]);
#pragma unroll
      for (int i = 0; i < 8; i++) s1[i] = f2bf(tile[seg * 16 + 8 + i][px]);
      short* dp = dst + ((size_t)(bid * 64 + px)) * 64 + seg * 16;
      *(bf16x8*)dp = s0;
      *(bf16x8*)(dp + 8) = s1;
    }
  }
}

// Weight prep, all 3 stages in one launch (stage = blockIdx.x/144).
__global__ __launch_bounds__(256) void prep_weights_all(
    const float* __restrict__ wd1, const float* __restrict__ wo1,
    short* __restrict__ wtd1, short* __restrict__ wtoff1,
    const float* __restrict__ wd2, const float* __restrict__ wo2,
    short* __restrict__ wtd2, short* __restrict__ wtoff2,
    const float* __restrict__ wd3, const float* __restrict__ wo3,
    short* __restrict__ wtd3, short* __restrict__ wtoff3) {
  const int s = blockIdx.x / 144;
  const float* wd = (s == 0) ? wd1 : (s == 1) ? wd2 : wd3;
  const float* wo = (s == 0) ? wo1 : (s == 1) ? wo2 : wo3;
  short* wtd = (s == 0) ? wtd1 : (s == 1) ? wtd2 : wtd3;
  short* wtoff = (s == 0) ? wtoff1 : (s == 1) ? wtoff2 : wtoff3;
  const int i = (blockIdx.x % 144) * 256 + threadIdx.x;  // 0..36863
  const int j = i & 7, l = (i >> 3) & 63, f = i >> 9;
  {
    int ot = f & 3, cf = (f >> 2) & 1, k = f >> 3;
    int o = ot * 16 + (l & 15), c = cf * 32 + (l >> 4) * 8 + j;
    wtd[i] = f2bf(wd[(o * 64 + c) * 9 + k]);
  }
  {
    int ot = f & 1, ks = f >> 1;
    int cs = ks & 3, k = ks >> 2;
    int o = ot * 16 + (l & 15), c = cs * 32 + (l >> 4) * 8 + j;
    wtoff[i] = (o < 18) ? f2bf(wo[(o * 128 + c) * 9 + k]) : (short)0;
  }
}

// ---------- MFMA offset conv, 2-deep pipelined ----------
#define OTAP_ADDR(k, s)                                                     \
  {                                                                         \
    const int ky = (k) / 3, kx = (k) - ky * 3;                              \
    const int hh = h + ky - 1, ww2 = w + kx - 1;                            \
    omask[s] = (hh >= 0) & (hh < HH) & (ww2 >= 0) & (ww2 < WW);             \
    const int ch = min(max(hh, 0), HH - 1), cw = min(max(ww2, 0), WW - 1);  \
    opb[s] = ((b * HW + ch * WW + cw) << 6) + c0;                           \
  }
#define OTAP_ISSUE(s)                                                       \
  ab[s][0] = *(const bf16x8*)(refb + opb[s]);                               \
  ab[s][1] = *(const bf16x8*)(refb + opb[s] + 32);                          \
  ab[s][2] = *(const bf16x8*)(x2b + opb[s]);                                \
  ab[s][3] = *(const bf16x8*)(x2b + opb[s] + 32);
#define OTAP_COMPUTE(k, s)                                                  \
  {                                                                         \
    _Pragma("unroll") for (int cs = 0; cs < 4; cs++) {                      \
      bf16x8 vv = omask[s] ? ab[s][cs] : (bf16x8)(short)0;                  \
      const int f = ((k) * 4 + cs) * 2;                                     \
      acc[0] = __builtin_amdgcn_mfma_f32_16x16x32_bf16(wp[f * 64], vv,      \
                                                       acc[0], 0, 0, 0);    \
      acc[1] = __builtin_amdgcn_mfma_f32_16x16x32_bf16(wp[(f + 1) * 64],    \
                                                       vv, acc[1], 0, 0, 0);\
    }                                                                       \
  }

__global__ __launch_bounds__(256, 2) void off_conv_kernel(
    const short* __restrict__ ref, const short* __restrict__ x2,
    const short* __restrict__ wtoff, const float* __restrict__ bias,
    float* __restrict__ out) {
  int bid = blockIdx.x;
  bid = (bid & 7) * (gridDim.x >> 3) + (bid >> 3);
  const int tid = threadIdx.x;
  const int l = tid & 63, wv = tid >> 6;
  const int col = l & 15, quad = l >> 4;
  const int pix = bid * 64 + wv * 16 + col;
  const int b = pix >> 14, hw = pix & (HW - 1);
  const int h = hw >> 7, w = hw & (WW - 1);

  f32x4 acc[2];
#pragma unroll
  for (int ot = 0; ot < 2; ot++)
#pragma unroll
    for (int r = 0; r < 4; r++) acc[ot][r] = 0.f;

  const int c0 = quad * 8;
  const bf16x8* wp = (const bf16x8*)wtoff + l;
  const short* refb = ref;
  const short* x2b = x2;

  bf16x8 ab[2][4];
  int opb[2];
  bool omask[2];

  OTAP_ADDR(0, 0) OTAP_ISSUE(0)
#pragma unroll
  for (int k = 0; k < 9; k++) {
    const int s = k & 1, ns = s ^ 1;
    if (k < 8) { OTAP_ADDR(k + 1, ns) OTAP_ISSUE(ns) }
    OTAP_COMPUTE(k, s)
  }

  float* po = out + (size_t)pix * OCP;
#pragma unroll
  for (int r = 0; r < 4; r++) po[quad * 4 + r] = acc[0][r] + bias[quad * 4 + r];
  if (quad == 0) {
    po[16] = acc[1][0] + bias[16];
    po[17] = acc[1][1] + bias[17];
  }
}

// ---------- MFMA deformable conv, 2-deep pipelined ----------
#define DTAP_ADDR(k, s)                                                     \
  {                                                                         \
    const int ky = (k) / 3, kx = (k) - ky * 3;                              \
    const float py = (float)(h - 1 + ky) + offv[2 * (k)];                   \
    const float pxx = (float)(w - 1 + kx) + offv[2 * (k) + 1];              \
    const float y0f = floorf(py), x0f = floorf(pxx);                        \
    const float ly = py - y0f, lx = pxx - x0f;                              \
    const int y0 = (int)y0f, x0 = (int)x0f;                                 \
    const int y1 = y0 + 1, x1 = x0 + 1;                                     \
    float w00 = (1.f - ly) * (1.f - lx);                                    \
    float w01 = (1.f - ly) * lx;                                            \
    float w10 = ly * (1.f - lx);                                            \
    float w11 = ly * lx;                                                    \
    if (y0 < 0 || y0 >= HH) { w00 = 0.f; w01 = 0.f; }                       \
    if (y1 < 0 || y1 >= HH) { w10 = 0.f; w11 = 0.f; }                       \
    if (x0 < 0 || x0 >= WW) { w00 = 0.f; w10 = 0.f; }                       \
    if (x1 < 0 || x1 >= WW) { w01 = 0.f; w11 = 0.f; }                       \
    const int cy0 = min(max(y0, 0), HH - 1), cy1 = min(max(y1, 0), HH - 1); \
    const int cx0 = min(max(x0, 0), WW - 1), cx1 = min(max(x1, 0), WW - 1); \
    pbuf[s][0] = ((cy0 * WW + cx0) << 6) + c0;                              \
    pbuf[s][1] = ((cy0 * WW + cx1) << 6) + c0;                              \
    pbuf[s][2] = ((cy1 * WW + cx0) << 6) + c0;                              \
    pbuf[s][3] = ((cy1 * WW + cx1) << 6) + c0;                              \
    wbuf[s][0] = w00; wbuf[s][1] = w01; wbuf[s][2] = w10; wbuf[s][3] = w11; \
  }
#define DTAP_ISSUE(s)                                                       \
  cbuf[s][0] = *(const bf16x8*)(xb + pbuf[s][0]);                           \
  cbuf[s][1] = *(const bf16x8*)(xb + pbuf[s][0] + 32);                      \
  cbuf[s][2] = *(const bf16x8*)(xb + pbuf[s][1]);                           \
  cbuf[s][3] = *(const bf16x8*)(xb + pbuf[s][1] + 32);                      \
  cbuf[s][4] = *(const bf16x8*)(xb + pbuf[s][2]);                           \
  cbuf[s][5] = *(const bf16x8*)(xb + pbuf[s][2] + 32);                      \
  cbuf[s][6] = *(const bf16x8*)(xb + pbuf[s][3]);                           \
  cbuf[s][7] = *(const bf16x8*)(xb + pbuf[s][3] + 32);
#define DTAP_COMPUTE(k, s)                                                  \
  {                                                                         \
    bf16x8 wf0 = wp[((k) * 8 + 0) * 64];                                    \
    bf16x8 wf1 = wp[((k) * 8 + 1) * 64];                                    \
    bf16x8 wf2 = wp[((k) * 8 + 2) * 64];                                    \
    bf16x8 wf3 = wp[((k) * 8 + 3) * 64];                                    \
    bf16x8 wf4 = wp[((k) * 8 + 4) * 64];                                    \
    bf16x8 wf5 = wp[((k) * 8 + 5) * 64];                                    \
    bf16x8 wf6 = wp[((k) * 8 + 6) * 64];                                    \
    bf16x8 wf7 = wp[((k) * 8 + 7) * 64];                                    \
    bf16x8 bs0, bs1;                                                        \
    _Pragma("unroll") for (int j = 0; j < 8; j++) {                         \
      float sa = bf2f(cbuf[s][0][j]) * wbuf[s][0] +                         \
                 bf2f(cbuf[s][2][j]) * wbuf[s][1] +                         \
                 bf2f(cbuf[s][4][j]) * wbuf[s][2] +                         \
                 bf2f(cbuf[s][6][j]) * wbuf[s][3];                          \
      bs0[j] = f2bf(sa);                                                    \
      float sb = bf2f(cbuf[s][1][j]) * wbuf[s][0] +                         \
                 bf2f(cbuf[s][3][j]) * wbuf[s][1] +                         \
                 bf2f(cbuf[s][5][j]) * wbuf[s][2] +                         \
                 bf2f(cbuf[s][7][j]) * wbuf[s][3];                          \
      bs1[j] = f2bf(sb);                                                    \
    }                                                                       \
    acc[0] = __builtin_amdgcn_mfma_f32_16x16x32_bf16(wf0, bs0, acc[0], 0, 0, 0); \
    acc[1] = __builtin_amdgcn_mfma_f32_16x16x32_bf16(wf1, bs0, acc[1], 0, 0, 0); \
    acc[2] = __builtin_amdgcn_mfma_f32_16x16x32_bf16(wf2, bs0, acc[2], 0, 0, 0); \
    acc[3] = __builtin_amdgcn_mfma_f32_16x16x32_bf16(wf3, bs0, acc[3], 0, 0, 0); \
    acc[0] = __builtin_amdgcn_mfma_f32_16x16x32_bf16(wf4, bs1, acc[0], 0, 0, 0); \
    acc[1] = __builtin_amdgcn_mfma_f32_16x16x32_bf16(wf5, bs1, acc[1], 0, 0, 0); \
    acc[2] = __builtin_amdgcn_mfma_f32_16x16x32_bf16(wf6, bs1, acc[2], 0, 0, 0); \
    acc[3] = __builtin_amdgcn_mfma_f32_16x16x32_bf16(wf7, bs1, acc[3], 0, 0, 0); \
  }

__global__ __launch_bounds__(256, 2) void deform_mfma_kernel(
    const short* __restrict__ x, const float* __restrict__ off,
    const short* __restrict__ wtd, const float* __restrict__ bias,
    float* __restrict__ outf, short* __restrict__ outb) {
  int bid = blockIdx.x;
  bid = (bid & 7) * (gridDim.x >> 3) + (bid >> 3);
  const int tid = threadIdx.x;
  const int l = tid & 63, wv = tid >> 6;
  const int col = l & 15, quad = l >> 4;
  const int pix = bid * 64 + wv * 16 + col;
  const int b = pix >> 14, hw = pix & (HW - 1);
  const int h = hw >> 7, w = hw & (WW - 1);

  const short* xb = x + (size_t)b * (HW * 64);
  const float* offp = off + (size_t)pix * OCP;

  f32x4 ov0 = *(const f32x4*)(offp);
  f32x4 ov1 = *(const f32x4*)(offp + 4);
  f32x4 ov2 = *(const f32x4*)(offp + 8);
  f32x4 ov3 = *(const f32x4*)(offp + 12);
  f32x2 ov4 = *(const f32x2*)(offp + 16);
  float offv[18];
#pragma unroll
  for (int i = 0; i < 4; i++) offv[i] = ov0[i];
#pragma unroll
  for (int i = 0; i < 4; i++) offv[4 + i] = ov1[i];
#pragma unroll
  for (int i = 0; i < 4; i++) offv[8 + i] = ov2[i];
#pragma unroll
  for (int i = 0; i < 4; i++) offv[12 + i] = ov3[i];
  offv[16] = ov4[0];
  offv[17] = ov4[1];

  f32x4 acc[4];
#pragma unroll
  for (int ot = 0; ot < 4; ot++)
#pragma unroll
    for (int r = 0; r < 4; r++) acc[ot][r] = bias[ot * 16 + quad * 4 + r];

  const int c0 = quad * 8;
  const bf16x8* wp = (const bf16x8*)wtd + l;

  bf16x8 cbuf[2][8];
  int pbuf[2][4];
  float wbuf[2][4];

  DTAP_ADDR(0, 0) DTAP_ISSUE(0)
#pragma unroll
  for (int k = 0; k < 9; k++) {
    const int s = k & 1, ns = s ^ 1;
    if (k < 8) { DTAP_ADDR(k + 1, ns) DTAP_ISSUE(ns) }
    DTAP_COMPUTE(k, s)
  }

  if (outb) {
#pragma unroll
    for (int ot = 0; ot < 4; ot++) {
      short4 sv;
      sv.x = f2bf(acc[ot][0]); sv.y = f2bf(acc[ot][1]);
      sv.z = f2bf(acc[ot][2]); sv.w = f2bf(acc[ot][3]);
      *(short4*)(outb + (size_t)pix * 64 + ot * 16 + quad * 4) = sv;
    }
  }
  if (outf) {
#pragma unroll
    for (int ot = 0; ot < 4; ot++)
#pragma unroll
      for (int r = 0; r < 4; r++) {
        const int o = ot * 16 + quad * 4 + r;
        outf[(size_t)b * (CC * HW) + (size_t)o * HW + hw] = acc[ot][r];
      }
  }
}

extern "C" void kernel_launch(void* const* d_in, const int* in_sizes, int n_in,
                              void* d_out, int out_size, void* d_ws, size_t ws_size,
                              hipStream_t stream) {
  const float* ref    = (const float*)d_in[0];
  const float* nbr    = (const float*)d_in[1];
  const float* w_off1 = (const float*)d_in[2];
  const float* b_off1 = (const float*)d_in[3];
  const float* w_d1   = (const float*)d_in[4];
  const float* b_d1   = (const float*)d_in[5];
  const float* w_off2 = (const float*)d_in[6];
  const float* b_off2 = (const float*)d_in[7];
  const float* w_d2   = (const float*)d_in[8];
  const float* b_d2   = (const float*)d_in[9];
  const float* w_off3 = (const float*)d_in[10];
  const float* b_off3 = (const float*)d_in[11];
  const float* w_d3   = (const float*)d_in[12];
  const float* b_d3   = (const float*)d_in[13];

  float* out = (float*)d_out;
  char* ws = (char*)d_ws;
  float* off_buf = (float*)(ws);               // 4*16384*20*4 = 5,242,880 B
  short* ref_bf  = (short*)(ws + 5242880);     // 8,388,608 B each
  short* nbr_bf  = (short*)(ws + 13631488);
  short* d1_bf   = (short*)(ws + 22020096);
  short* d2_bf   = (short*)(ws + 30408704);
  short* wtd1    = (short*)(ws + 38797312);    // 73,728 B each
  short* wtd2    = (short*)(ws + 38871040);
  short* wtd3    = (short*)(ws + 38944768);
  short* wtoff1  = (short*)(ws + 39018496);
  short* wtoff2  = (short*)(ws + 39092224);
  short* wtoff3  = (short*)(ws + 39165952);

  cast_nhwc_kernel<<<1024, 256, 0, stream>>>(ref, nbr, ref_bf, nbr_bf);
  prep_weights_all<<<432, 256, 0, stream>>>(
      w_d1, w_off1, wtd1, wtoff1,
      w_d2, w_off2, wtd2, wtoff2,
      w_d3, w_off3, wtd3, wtoff3);

  const int nblk = BB * HW / 64;  // 1024

  off_conv_kernel<<<nblk, 256, 0, stream>>>(ref_bf, nbr_bf, wtoff1, b_off1, off_buf);
  deform_mfma_kernel<<<nblk, 256, 0, stream>>>(nbr_bf, off_buf, wtd1, b_d1, nullptr, d1_bf);
  off_conv_kernel<<<nblk, 256, 0, stream>>>(ref_bf, d1_bf, wtoff2, b_off2, off_buf);
  deform_mfma_kernel<<<nblk, 256, 0, stream>>>(d1_bf, off_buf, wtd2, b_d2, nullptr, d2_bf);
  off_conv_kernel<<<nblk, 256, 0, stream>>>(ref_bf, d2_bf, wtoff3, b_off3, off_buf);
  deform_mfma_kernel<<<nblk, 256, 0, stream>>>(d2_bf, off_buf, wtd3, b_d3, out, nullptr);
}

// Round 7
// 217.046 us; speedup vs baseline: 1.0104x; 1.0104x over previous
//
#include <hip/hip_runtime.h>
#include <hip/hip_bf16.h>

#define BB 4
#define CC 64
#define HH 128
#define WW 128
#define HW (HH * WW)
#define OCP 20  // offset channels, padded (18 used)

typedef short bf16x8 __attribute__((ext_vector_type(8)));
typedef float f32x4 __attribute__((ext_vector_type(4)));
typedef float f32x2 __attribute__((ext_vector_type(2)));

static __device__ __forceinline__ short f2bf(float f) {
  __hip_bfloat16 h = __float2bfloat16(f);
  return __builtin_bit_cast(short, h);
}
static __device__ __forceinline__ float bf2f(short s) {
  unsigned int u = ((unsigned int)(unsigned short)s) << 16;
  return __builtin_bit_cast(float, u);
}

// NCHW f32 -> NHWC bf16 for two tensors. Block = 64 px x 64 c tile.
__global__ __launch_bounds__(256) void cast_nhwc_kernel(
    const float* __restrict__ a, const float* __restrict__ b,
    short* __restrict__ oa, short* __restrict__ ob) {
  __shared__ float tile[64][68];
  const int bid = blockIdx.x;        // 1024 blocks
  const int bb = bid >> 8;           // batch
  const int hw0 = (bid & 255) * 64;  // 64-px stripe
  const int t = threadIdx.x;
  for (int s = 0; s < 2; s++) {
    const float* src = s ? b : a;
    short* dst = s ? ob : oa;
    if (s) __syncthreads();
    {
      const int lp = t & 15;  // 16 lanes x float4 = 64 px
      for (int c = (t >> 4); c < 64; c += 16) {
        float4 v = *(const float4*)&src[((size_t)(bb * 64 + c)) * HW + hw0 + lp * 4];
        *(float4*)&tile[c][lp * 4] = v;
      }
    }
    __syncthreads();
    {
      const int px = t >> 2;
      const int seg = t & 3;
      bf16x8 s0, s1;
#pragma unroll
      for (int i = 0; i < 8; i++) s0[i] = f2bf(tile[seg * 16 + i][px]);
#pragma unroll
      for (int i = 0; i < 8; i++) s1[i] = f2bf(tile[seg * 16 + 8 + i][px]);
      short* dp = dst + ((size_t)(bid * 64 + px)) * 64 + seg * 16;
      *(bf16x8*)dp = s0;
      *(bf16x8*)(dp + 8) = s1;
    }
  }
}

// Weight prep, all 3 stages in one launch (stage = blockIdx.x/144).
__global__ __launch_bounds__(256) void prep_weights_all(
    const float* __restrict__ wd1, const float* __restrict__ wo1,
    short* __restrict__ wtd1, short* __restrict__ wtoff1,
    const float* __restrict__ wd2, const float* __restrict__ wo2,
    short* __restrict__ wtd2, short* __restrict__ wtoff2,
    const float* __restrict__ wd3, const float* __restrict__ wo3,
    short* __restrict__ wtd3, short* __restrict__ wtoff3) {
  const int s = blockIdx.x / 144;
  const float* wd = (s == 0) ? wd1 : (s == 1) ? wd2 : wd3;
  const float* wo = (s == 0) ? wo1 : (s == 1) ? wo2 : wo3;
  short* wtd = (s == 0) ? wtd1 : (s == 1) ? wtd2 : wtd3;
  short* wtoff = (s == 0) ? wtoff1 : (s == 1) ? wtoff2 : wtoff3;
  const int i = (blockIdx.x % 144) * 256 + threadIdx.x;  // 0..36863
  const int j = i & 7, l = (i >> 3) & 63, f = i >> 9;
  {
    int ot = f & 3, cf = (f >> 2) & 1, k = f >> 3;
    int o = ot * 16 + (l & 15), c = cf * 32 + (l >> 4) * 8 + j;
    wtd[i] = f2bf(wd[(o * 64 + c) * 9 + k]);
  }
  {
    int ot = f & 1, ks = f >> 1;
    int cs = ks & 3, k = ks >> 2;
    int o = ot * 16 + (l & 15), c = cs * 32 + (l >> 4) * 8 + j;
    wtoff[i] = (o < 18) ? f2bf(wo[(o * 128 + c) * 9 + k]) : (short)0;
  }
}

// ---------- MFMA offset conv: 3-tap groups, batch-issued loads ----------
#define OTAP_ADDR(k, t)                                                     \
  {                                                                         \
    const int ky = (k) / 3, kx = (k) - ky * 3;                              \
    const int hh = h + ky - 1, ww2 = w + kx - 1;                            \
    om[t] = (hh >= 0) & (hh < HH) & (ww2 >= 0) & (ww2 < WW);                \
    const int ch = min(max(hh, 0), HH - 1), cw = min(max(ww2, 0), WW - 1);  \
    ob_[t] = ((b * HW + ch * WW + cw) << 6) + c0;                           \
  }
#define OTAP_ISSUE(k, t)                                                    \
  oact[(t) * 4 + 0] = *(const bf16x8*)(refb + ob_[t]);                      \
  oact[(t) * 4 + 1] = *(const bf16x8*)(refb + ob_[t] + 32);                 \
  oact[(t) * 4 + 2] = *(const bf16x8*)(x2b + ob_[t]);                       \
  oact[(t) * 4 + 3] = *(const bf16x8*)(x2b + ob_[t] + 32);                  \
  owf[(t) * 8 + 0] = wp[(((k) * 4 + 0) * 2 + 0) * 64];                      \
  owf[(t) * 8 + 1] = wp[(((k) * 4 + 0) * 2 + 1) * 64];                      \
  owf[(t) * 8 + 2] = wp[(((k) * 4 + 1) * 2 + 0) * 64];                      \
  owf[(t) * 8 + 3] = wp[(((k) * 4 + 1) * 2 + 1) * 64];                      \
  owf[(t) * 8 + 4] = wp[(((k) * 4 + 2) * 2 + 0) * 64];                      \
  owf[(t) * 8 + 5] = wp[(((k) * 4 + 2) * 2 + 1) * 64];                      \
  owf[(t) * 8 + 6] = wp[(((k) * 4 + 3) * 2 + 0) * 64];                      \
  owf[(t) * 8 + 7] = wp[(((k) * 4 + 3) * 2 + 1) * 64];
#define OTAP_COMP(k, t)                                                     \
  {                                                                         \
    _Pragma("unroll") for (int cs = 0; cs < 4; cs++) {                      \
      bf16x8 vv = om[t] ? oact[(t) * 4 + cs] : (bf16x8)(short)0;            \
      acc[0] = __builtin_amdgcn_mfma_f32_16x16x32_bf16(                     \
          owf[(t) * 8 + cs * 2], vv, acc[0], 0, 0, 0);                      \
      acc[1] = __builtin_amdgcn_mfma_f32_16x16x32_bf16(                     \
          owf[(t) * 8 + cs * 2 + 1], vv, acc[1], 0, 0, 0);                  \
    }                                                                       \
  }

__global__ __launch_bounds__(256, 2) void off_conv_kernel(
    const short* __restrict__ ref, const short* __restrict__ x2,
    const short* __restrict__ wtoff, const float* __restrict__ bias,
    float* __restrict__ out) {
  int bid = blockIdx.x;
  bid = (bid & 7) * (gridDim.x >> 3) + (bid >> 3);
  const int tid = threadIdx.x;
  const int l = tid & 63, wv = tid >> 6;
  const int col = l & 15, quad = l >> 4;
  const int pix = bid * 64 + wv * 16 + col;
  const int b = pix >> 14, hw = pix & (HW - 1);
  const int h = hw >> 7, w = hw & (WW - 1);

  f32x4 acc[2];
#pragma unroll
  for (int ot = 0; ot < 2; ot++)
#pragma unroll
    for (int r = 0; r < 4; r++) acc[ot][r] = 0.f;

  const int c0 = quad * 8;
  const bf16x8* wp = (const bf16x8*)wtoff + l;
  const short* refb = ref;
  const short* x2b = x2;

  bf16x8 oact[12];
  bf16x8 owf[24];
  int ob_[3];
  bool om[3];

#pragma unroll
  for (int G = 0; G < 3; G++) {
    const int k0 = G * 3;
    OTAP_ADDR(k0 + 0, 0) OTAP_ISSUE(k0 + 0, 0)
    OTAP_ADDR(k0 + 1, 1) OTAP_ISSUE(k0 + 1, 1)
    OTAP_ADDR(k0 + 2, 2) OTAP_ISSUE(k0 + 2, 2)
    __builtin_amdgcn_sched_barrier(0);
    OTAP_COMP(k0 + 0, 0)
    OTAP_COMP(k0 + 1, 1)
    OTAP_COMP(k0 + 2, 2)
  }

  float* po = out + (size_t)pix * OCP;
#pragma unroll
  for (int r = 0; r < 4; r++) po[quad * 4 + r] = acc[0][r] + bias[quad * 4 + r];
  if (quad == 0) {
    po[16] = acc[1][0] + bias[16];
    po[17] = acc[1][1] + bias[17];
  }
}

// ---------- MFMA deformable conv: 2-tap groups, batch-issued loads ----------
#define DTAP_ADDR(k, t)                                                     \
  {                                                                         \
    const int ky = (k) / 3, kx = (k) - ky * 3;                              \
    const float py = (float)(h - 1 + ky) + offv[2 * (k)];                   \
    const float pxx = (float)(w - 1 + kx) + offv[2 * (k) + 1];              \
    const float y0f = floorf(py), x0f = floorf(pxx);                        \
    const float ly = py - y0f, lx = pxx - x0f;                              \
    const int y0 = (int)y0f, x0 = (int)x0f;                                 \
    const int y1 = y0 + 1, x1 = x0 + 1;                                     \
    float w00 = (1.f - ly) * (1.f - lx), w01 = (1.f - ly) * lx;             \
    float w10 = ly * (1.f - lx), w11 = ly * lx;                             \
    if (y0 < 0 || y0 >= HH) { w00 = 0.f; w01 = 0.f; }                       \
    if (y1 < 0 || y1 >= HH) { w10 = 0.f; w11 = 0.f; }                       \
    if (x0 < 0 || x0 >= WW) { w00 = 0.f; w10 = 0.f; }                       \
    if (x1 < 0 || x1 >= WW) { w01 = 0.f; w11 = 0.f; }                       \
    const int cy0 = min(max(y0, 0), HH - 1), cy1 = min(max(y1, 0), HH - 1); \
    const int cx0 = min(max(x0, 0), WW - 1), cx1 = min(max(x1, 0), WW - 1); \
    pb[(t) * 4 + 0] = ((cy0 * WW + cx0) << 6) + c0;                         \
    pb[(t) * 4 + 1] = ((cy0 * WW + cx1) << 6) + c0;                         \
    pb[(t) * 4 + 2] = ((cy1 * WW + cx0) << 6) + c0;                         \
    pb[(t) * 4 + 3] = ((cy1 * WW + cx1) << 6) + c0;                         \
    wb[(t) * 4 + 0] = w00; wb[(t) * 4 + 1] = w01;                           \
    wb[(t) * 4 + 2] = w10; wb[(t) * 4 + 3] = w11;                           \
  }
#define DTAP_ISSUE(k, t)                                                    \
  act[(t) * 8 + 0] = *(const bf16x8*)(xb + pb[(t) * 4 + 0]);                \
  act[(t) * 8 + 1] = *(const bf16x8*)(xb + pb[(t) * 4 + 0] + 32);           \
  act[(t) * 8 + 2] = *(const bf16x8*)(xb + pb[(t) * 4 + 1]);                \
  act[(t) * 8 + 3] = *(const bf16x8*)(xb + pb[(t) * 4 + 1] + 32);           \
  act[(t) * 8 + 4] = *(const bf16x8*)(xb + pb[(t) * 4 + 2]);                \
  act[(t) * 8 + 5] = *(const bf16x8*)(xb + pb[(t) * 4 + 2] + 32);           \
  act[(t) * 8 + 6] = *(const bf16x8*)(xb + pb[(t) * 4 + 3]);                \
  act[(t) * 8 + 7] = *(const bf16x8*)(xb + pb[(t) * 4 + 3] + 32);           \
  wfr[(t) * 8 + 0] = wp[((k) * 8 + 0) * 64];                                \
  wfr[(t) * 8 + 1] = wp[((k) * 8 + 1) * 64];                                \
  wfr[(t) * 8 + 2] = wp[((k) * 8 + 2) * 64];                                \
  wfr[(t) * 8 + 3] = wp[((k) * 8 + 3) * 64];                                \
  wfr[(t) * 8 + 4] = wp[((k) * 8 + 4) * 64];                                \
  wfr[(t) * 8 + 5] = wp[((k) * 8 + 5) * 64];                                \
  wfr[(t) * 8 + 6] = wp[((k) * 8 + 6) * 64];                                \
  wfr[(t) * 8 + 7] = wp[((k) * 8 + 7) * 64];
#define DTAP_COMP(k, t)                                                     \
  {                                                                         \
    bf16x8 bs0, bs1;                                                        \
    _Pragma("unroll") for (int j = 0; j < 8; j++) {                         \
      float sa = bf2f(act[(t) * 8 + 0][j]) * wb[(t) * 4 + 0] +              \
                 bf2f(act[(t) * 8 + 2][j]) * wb[(t) * 4 + 1] +              \
                 bf2f(act[(t) * 8 + 4][j]) * wb[(t) * 4 + 2] +              \
                 bf2f(act[(t) * 8 + 6][j]) * wb[(t) * 4 + 3];               \
      bs0[j] = f2bf(sa);                                                    \
      float sb = bf2f(act[(t) * 8 + 1][j]) * wb[(t) * 4 + 0] +              \
                 bf2f(act[(t) * 8 + 3][j]) * wb[(t) * 4 + 1] +              \
                 bf2f(act[(t) * 8 + 5][j]) * wb[(t) * 4 + 2] +              \
                 bf2f(act[(t) * 8 + 7][j]) * wb[(t) * 4 + 3];               \
      bs1[j] = f2bf(sb);                                                    \
    }                                                                       \
    acc[0] = __builtin_amdgcn_mfma_f32_16x16x32_bf16(wfr[(t) * 8 + 0], bs0, acc[0], 0, 0, 0); \
    acc[1] = __builtin_amdgcn_mfma_f32_16x16x32_bf16(wfr[(t) * 8 + 1], bs0, acc[1], 0, 0, 0); \
    acc[2] = __builtin_amdgcn_mfma_f32_16x16x32_bf16(wfr[(t) * 8 + 2], bs0, acc[2], 0, 0, 0); \
    acc[3] = __builtin_amdgcn_mfma_f32_16x16x32_bf16(wfr[(t) * 8 + 3], bs0, acc[3], 0, 0, 0); \
    acc[0] = __builtin_amdgcn_mfma_f32_16x16x32_bf16(wfr[(t) * 8 + 4], bs1, acc[0], 0, 0, 0); \
    acc[1] = __builtin_amdgcn_mfma_f32_16x16x32_bf16(wfr[(t) * 8 + 5], bs1, acc[1], 0, 0, 0); \
    acc[2] = __builtin_amdgcn_mfma_f32_16x16x32_bf16(wfr[(t) * 8 + 6], bs1, acc[2], 0, 0, 0); \
    acc[3] = __builtin_amdgcn_mfma_f32_16x16x32_bf16(wfr[(t) * 8 + 7], bs1, acc[3], 0, 0, 0); \
  }

__global__ __launch_bounds__(256, 2) void deform_mfma_kernel(
    const short* __restrict__ x, const float* __restrict__ off,
    const short* __restrict__ wtd, const float* __restrict__ bias,
    float* __restrict__ outf, short* __restrict__ outb) {
  int bid = blockIdx.x;
  bid = (bid & 7) * (gridDim.x >> 3) + (bid >> 3);
  const int tid = threadIdx.x;
  const int l = tid & 63, wv = tid >> 6;
  const int col = l & 15, quad = l >> 4;
  const int pix = bid * 64 + wv * 16 + col;
  const int b = pix >> 14, hw = pix & (HW - 1);
  const int h = hw >> 7, w = hw & (WW - 1);

  const short* xb = x + (size_t)b * (HW * 64);
  const float* offp = off + (size_t)pix * OCP;

  f32x4 ov0 = *(const f32x4*)(offp);
  f32x4 ov1 = *(const f32x4*)(offp + 4);
  f32x4 ov2 = *(const f32x4*)(offp + 8);
  f32x4 ov3 = *(const f32x4*)(offp + 12);
  f32x2 ov4 = *(const f32x2*)(offp + 16);
  float offv[18];
#pragma unroll
  for (int i = 0; i < 4; i++) offv[i] = ov0[i];
#pragma unroll
  for (int i = 0; i < 4; i++) offv[4 + i] = ov1[i];
#pragma unroll
  for (int i = 0; i < 4; i++) offv[8 + i] = ov2[i];
#pragma unroll
  for (int i = 0; i < 4; i++) offv[12 + i] = ov3[i];
  offv[16] = ov4[0];
  offv[17] = ov4[1];

  f32x4 acc[4];
#pragma unroll
  for (int ot = 0; ot < 4; ot++)
#pragma unroll
    for (int r = 0; r < 4; r++) acc[ot][r] = bias[ot * 16 + quad * 4 + r];

  const int c0 = quad * 8;
  const bf16x8* wp = (const bf16x8*)wtd + l;

  bf16x8 act[16];
  bf16x8 wfr[16];
  int pb[8];
  float wb[8];

#pragma unroll
  for (int G = 0; G < 5; G++) {
    const int k0 = G * 2;
    DTAP_ADDR(k0, 0) DTAP_ISSUE(k0, 0)
    if (k0 + 1 < 9) { DTAP_ADDR(k0 + 1, 1) DTAP_ISSUE(k0 + 1, 1) }
    __builtin_amdgcn_sched_barrier(0);
    DTAP_COMP(k0, 0)
    if (k0 + 1 < 9) DTAP_COMP(k0 + 1, 1)
  }

  if (outb) {
#pragma unroll
    for (int ot = 0; ot < 4; ot++) {
      short4 sv;
      sv.x = f2bf(acc[ot][0]); sv.y = f2bf(acc[ot][1]);
      sv.z = f2bf(acc[ot][2]); sv.w = f2bf(acc[ot][3]);
      *(short4*)(outb + (size_t)pix * 64 + ot * 16 + quad * 4) = sv;
    }
  }
  if (outf) {
#pragma unroll
    for (int ot = 0; ot < 4; ot++)
#pragma unroll
      for (int r = 0; r < 4; r++) {
        const int o = ot * 16 + quad * 4 + r;
        outf[(size_t)b * (CC * HW) + (size_t)o * HW + hw] = acc[ot][r];
      }
  }
}

extern "C" void kernel_launch(void* const* d_in, const int* in_sizes, int n_in,
                              void* d_out, int out_size, void* d_ws, size_t ws_size,
                              hipStream_t stream) {
  const float* ref    = (const float*)d_in[0];
  const float* nbr    = (const float*)d_in[1];
  const float* w_off1 = (const float*)d_in[2];
  const float* b_off1 = (const float*)d_in[3];
  const float* w_d1   = (const float*)d_in[4];
  const float* b_d1   = (const float*)d_in[5];
  const float* w_off2 = (const float*)d_in[6];
  const float* b_off2 = (const float*)d_in[7];
  const float* w_d2   = (const float*)d_in[8];
  const float* b_d2   = (const float*)d_in[9];
  const float* w_off3 = (const float*)d_in[10];
  const float* b_off3 = (const float*)d_in[11];
  const float* w_d3   = (const float*)d_in[12];
  const float* b_d3   = (const float*)d_in[13];

  float* out = (float*)d_out;
  char* ws = (char*)d_ws;
  float* off_buf = (float*)(ws);               // 4*16384*20*4 = 5,242,880 B
  short* ref_bf  = (short*)(ws + 5242880);     // 8,388,608 B each
  short* nbr_bf  = (short*)(ws + 13631488);
  short* d1_bf   = (short*)(ws + 22020096);
  short* d2_bf   = (short*)(ws + 30408704);
  short* wtd1    = (short*)(ws + 38797312);    // 73,728 B each
  short* wtd2    = (short*)(ws + 38871040);
  short* wtd3    = (short*)(ws + 38944768);
  short* wtoff1  = (short*)(ws + 39018496);
  short* wtoff2  = (short*)(ws + 39092224);
  short* wtoff3  = (short*)(ws + 39165952);

  cast_nhwc_kernel<<<1024, 256, 0, stream>>>(ref, nbr, ref_bf, nbr_bf);
  prep_weights_all<<<432, 256, 0, stream>>>(
      w_d1, w_off1, wtd1, wtoff1,
      w_d2, w_off2, wtd2, wtoff2,
      w_d3, w_off3, wtd3, wtoff3);

  const int nblk = BB * HW / 64;  // 1024

  off_conv_kernel<<<nblk, 256, 0, stream>>>(ref_bf, nbr_bf, wtoff1, b_off1, off_buf);
  deform_mfma_kernel<<<nblk, 256, 0, stream>>>(nbr_bf, off_buf, wtd1, b_d1, nullptr, d1_bf);
  off_conv_kernel<<<nblk, 256, 0, stream>>>(ref_bf, d1_bf, wtoff2, b_off2, off_buf);
  deform_mfma_kernel<<<nblk, 256, 0, stream>>>(d1_bf, off_buf, wtd2, b_d2, nullptr, d2_bf);
  off_conv_kernel<<<nblk, 256, 0, stream>>>(ref_bf, d2_bf, wtoff3, b_off3, off_buf);
  deform_mfma_kernel<<<nblk, 256, 0, stream>>>(d2_bf, off_buf, wtd3, b_d3, out, nullptr);
}